// Round 11
// baseline (227.476 us; speedup 1.0000x reference)
//
#include <hip/hip_runtime.h>
#include <hip/hip_bf16.h>

// Problem constants
#define T_  4096
#define Bb  2
#define Nn  2048
#define Cc  768
#define Ee  24
#define Dd  64
#define Hh  12
#define KR  1568   // reduce GEMM K: 1536 (W_out) + 24 (b_out via dense gates) + 8 pad
#define KS  16     // gate k-split
#define KC  48     // 768 / KS
#define NB2 1024   // gate2 block count (T_/4)
#define SCL 0.18033688f   // 0.125 * log2(e) — folded into q at GEMM epilogue

typedef __attribute__((ext_vector_type(8))) short bf16x8;
typedef __attribute__((ext_vector_type(4))) short bf16x4;
typedef __attribute__((ext_vector_type(4))) float f32x4;

__device__ __forceinline__ unsigned short f2bf(float f) {
  union { float f; unsigned int i; } u; u.f = f;
  unsigned int r = u.i + 0x7FFFu + ((u.i >> 16) & 1u);
  return (unsigned short)(r >> 16);
}
__device__ __forceinline__ float bf2f(unsigned short s) {
  union { unsigned int i; float f; } u; u.i = ((unsigned int)s) << 16; return u.f;
}

__device__ __forceinline__ void gload16(const void* g, void* l) {
  __builtin_amdgcn_global_load_lds(
      (const __attribute__((address_space(1))) void*)g,
      (__attribute__((address_space(3))) void*)l, 16, 0, 0);
}

// ---------------------------------------------------------------------------
// Conversion kernels (weights -> bf16 B^T layouts)
// ---------------------------------------------------------------------------
__global__ __launch_bounds__(256) void convert_win_kernel(
    const float* __restrict__ W_in, unsigned short* __restrict__ BqT)
{
  __shared__ float ls[64][65];
  const int e = blockIdx.x, c0 = blockIdx.y * 64, tid = threadIdx.x;
  #pragma unroll
  for (int i = 0; i < 16; ++i) {
    int L = tid + i * 256, c = L >> 6, d = L & 63;
    ls[c][d] = W_in[(size_t)e * Cc * Dd + (size_t)(c0 + c) * Dd + d];
  }
  __syncthreads();
  #pragma unroll
  for (int i = 0; i < 16; ++i) {
    int L = tid + i * 256, d = L >> 6, c = L & 63;
    BqT[(size_t)(e * Dd + d) * Cc + c0 + c] = f2bf(ls[c][d]);
  }
}

__global__ __launch_bounds__(256) void convert_wout_kernel(
    const float* __restrict__ W_out, const float* __restrict__ b_out,
    unsigned short* __restrict__ BrT)
{
  __shared__ float ls[32][65];
  const int k0 = blockIdx.x * 32, n0 = blockIdx.y * 64, tid = threadIdx.x;
  #pragma unroll
  for (int i = 0; i < 8; ++i) {
    int L = tid + i * 256, k = L >> 6, n = L & 63;
    int kk = k0 + k;
    float v = (kk < 1536) ? W_out[(size_t)kk * Cc + n0 + n]
            : (kk < 1560) ? b_out[(size_t)(kk - 1536) * Cc + n0 + n] : 0.f;
    ls[k][n] = v;
  }
  __syncthreads();
  #pragma unroll
  for (int i = 0; i < 8; ++i) {
    int L = tid + i * 256, n = L >> 5, k = L & 31;
    BrT[(size_t)(n0 + n) * KR + k0 + k] = f2bf(ls[k][n]);
  }
}

__global__ __launch_bounds__(256) void convert_wkv_kernel(
    const float* __restrict__ W_kv, unsigned short* __restrict__ BkvT)
{
  __shared__ float ls[64][129];
  const int c0 = blockIdx.x * 64, tid = threadIdx.x;
  #pragma unroll
  for (int i = 0; i < 32; ++i) {
    int L = tid + i * 256, c = L >> 7, j = L & 127;
    ls[c][j] = W_kv[(size_t)(c0 + c) * 128 + j];
  }
  __syncthreads();
  #pragma unroll
  for (int i = 0; i < 32; ++i) {
    int L = tid + i * 256, j = L >> 6, c = L & 63;
    BkvT[(size_t)j * Cc + c0 + c] = f2bf(ls[c][j]);
  }
}

// ---------------------------------------------------------------------------
// bf16 MFMA GEMM: C = A[M][K] @ BT[N][K]^T (+bias).  Tile BM x 128, BK=32.
// MODE 0: f32 out (reduce GEMM).
// MODE 1: fused qall+kv.  BT = [BqT(1536) ; BkvT(128)] contiguous.
//   col < 1536 -> qallb (+b_in), PRE-SCALED by SCL
//   1536..1599 -> kbuf [B][N][D] (+b_kv lo)
//   1600..1663 -> vtbuf [B][D][N] (+b_kv hi), KEY-PERMUTED within each
//                 64-key block: pos = q<<4 | kg<<2 | r for key = kg<<4|q<<2|r
//                 (lets attn read V fragments as contiguous b128)
// ---------------------------------------------------------------------------
template<int MODE, int BM>
__global__ __launch_bounds__(256) void gemm_bt_kernel(
    const unsigned short* __restrict__ A, const unsigned short* __restrict__ BT,
    const float* __restrict__ bias, const float* __restrict__ bias2,
    void* __restrict__ Cout, void* __restrict__ Cout2, void* __restrict__ Cout3,
    int K, int ldc)
{
  constexpr int MI = BM / 32;
  __shared__ __align__(16) unsigned short As[BM * 32];
  __shared__ __align__(16) unsigned short Bs[128 * 32];
  const int tid = threadIdx.x, w = tid >> 6, lane = tid & 63;
  const int quad = lane >> 4, nl = lane & 15;
  const int m0 = blockIdx.x * BM, n0 = blockIdx.y * 128;
  const int mw = (w & 1) * (BM / 2), nw = (w >> 1) * 64;

  f32x4 acc[MI][4];
  #pragma unroll
  for (int i = 0; i < MI; ++i)
    #pragma unroll
    for (int j = 0; j < 4; ++j) acc[i][j] = (f32x4){0.f, 0.f, 0.f, 0.f};

  const int rlane = lane >> 2, col8 = (lane & 3) * 8;
  const int row0a = w * (BM / 4) + rlane;
  const int row0b = w * 32 + rlane;
  const unsigned short* a0 = A + (size_t)(m0 + row0a) * K + col8;
  const unsigned short* a1 = a0 + (size_t)16 * K;
  const unsigned short* b0 = BT + (size_t)(n0 + row0b) * K + col8;
  const unsigned short* b1 = b0 + (size_t)16 * K;
  unsigned short* lA0 = As + (w * (BM / 4)) * 32;
  unsigned short* lA1 = As + (w * (BM / 4) + 16) * 32;
  unsigned short* lB0 = Bs + (w * 32) * 32;
  unsigned short* lB1 = Bs + (w * 32 + 16) * 32;

  for (int k0 = 0; k0 < K; k0 += 32) {
    gload16(a0 + k0, lA0);
    if (BM == 128) gload16(a1 + k0, lA1);
    gload16(b0 + k0, lB0);
    gload16(b1 + k0, lB1);
    __syncthreads();

    bf16x8 af[MI], bfr[4];
    #pragma unroll
    for (int mi = 0; mi < MI; ++mi)
      af[mi] = *(const bf16x8*)&As[(mw + mi * 16 + nl) * 32 + quad * 8];
    #pragma unroll
    for (int ni = 0; ni < 4; ++ni)
      bfr[ni] = *(const bf16x8*)&Bs[(nw + ni * 16 + nl) * 32 + quad * 8];
    #pragma unroll
    for (int mi = 0; mi < MI; ++mi)
      #pragma unroll
      for (int ni = 0; ni < 4; ++ni)
        acc[mi][ni] = __builtin_amdgcn_mfma_f32_16x16x32_bf16(
            af[mi], bfr[ni], acc[mi][ni], 0, 0, 0);
    __syncthreads();
  }

  #pragma unroll
  for (int mi = 0; mi < MI; ++mi) {
    int rowb = m0 + mw + mi * 16 + quad * 4;
    int bb = rowb >> 11, nn = rowb & (Nn - 1);
    #pragma unroll
    for (int ni = 0; ni < 4; ++ni) {
      int col = n0 + nw + ni * 16 + nl;
      if (MODE == 0) {
        #pragma unroll
        for (int reg = 0; reg < 4; ++reg)
          ((float*)Cout)[(size_t)(rowb + reg) * ldc + col] = acc[mi][ni][reg];
      } else {
        if (col < 1536) {
          float bv = bias[col];
          #pragma unroll
          for (int reg = 0; reg < 4; ++reg)
            ((unsigned short*)Cout)[(size_t)(rowb + reg) * 1536 + col] =
                f2bf((acc[mi][ni][reg] + bv) * SCL);
        } else {
          int c2 = col - 1536;
          float bv = bias2[c2];
          if (c2 < Dd) {
            #pragma unroll
            for (int reg = 0; reg < 4; ++reg)
              ((unsigned short*)Cout2)[((size_t)bb * Nn + nn + reg) * Dd + c2] =
                  f2bf(acc[mi][ni][reg] + bv);
          } else {
            // key-permuted V^T write: nn ≡ 0 mod 4, swap bit-fields [5:4]<->[3:2]
            int np = (nn & ~63) | (((nn >> 2) & 3) << 4) | (((nn >> 4) & 3) << 2);
            ushort4 v;
            v.x = f2bf(acc[mi][ni][0] + bv);
            v.y = f2bf(acc[mi][ni][1] + bv);
            v.z = f2bf(acc[mi][ni][2] + bv);
            v.w = f2bf(acc[mi][ni][3] + bv);
            *(ushort4*)((unsigned short*)Cout3 +
                        ((size_t)bb * Dd + (c2 - Dd)) * Nn + np) = v;
          }
        }
      }
    }
  }
}

// ---------------------------------------------------------------------------
// gate1: partial logits + fused x->bf16 conversion
// ---------------------------------------------------------------------------
#define XPAD 52
__global__ __launch_bounds__(256) void gate1_kernel(
    const float* __restrict__ x, const float* __restrict__ wg,
    float* __restrict__ partial, unsigned short* __restrict__ xb)
{
  __shared__ __align__(16) float xs[256 * XPAD];
  __shared__ __align__(16) float wsT[Ee * KC];
  const int tid = threadIdx.x;
  const int t0 = blockIdx.x * 256;
  const int s = blockIdx.y, k0 = s * KC;

  #pragma unroll
  for (int i = 0; i < 12; ++i) {
    int f = tid + i * 256;
    int token = f / 12, j = f % 12;
    size_t gofs = (size_t)(t0 + token) * Cc + k0 + j * 4;
    float4 v = *(const float4*)&x[gofs];
    *(float4*)&xs[token * XPAD + j * 4] = v;
    ushort4 o;
    o.x = f2bf(v.x); o.y = f2bf(v.y); o.z = f2bf(v.z); o.w = f2bf(v.w);
    *(ushort4*)&xb[gofs] = o;
  }
  for (int i = tid; i < Ee * KC; i += 256)
    wsT[(i % Ee) * KC + i / Ee] = wg[k0 * Ee + i];
  __syncthreads();

  float xr[KC];
  #pragma unroll
  for (int kg = 0; kg < KC / 4; ++kg)
    *(float4*)&xr[kg * 4] = *(const float4*)&xs[tid * XPAD + kg * 4];

  float acc[Ee];
  #pragma unroll
  for (int e = 0; e < Ee; ++e) acc[e] = 0.f;
  #pragma unroll
  for (int e = 0; e < Ee; ++e) {
    #pragma unroll
    for (int kg = 0; kg < KC / 4; ++kg) {
      float4 wv = *(const float4*)&wsT[e * KC + kg * 4];
      acc[e] += xr[kg * 4 + 0] * wv.x + xr[kg * 4 + 1] * wv.y
              + xr[kg * 4 + 2] * wv.z + xr[kg * 4 + 3] * wv.w;
    }
  }

  float* dst = partial + ((size_t)(t0 + tid) * KS + s) * Ee;
  #pragma unroll
  for (int eg = 0; eg < Ee / 4; ++eg)
    *(float4*)&dst[eg * 4] = *(float4*)&acc[eg * 4];
}

// ---------------------------------------------------------------------------
// gate2: logits -> softmax -> top-12 -> gates; block stats -> bstats
// ---------------------------------------------------------------------------
__global__ __launch_bounds__(256) void gate2_kernel(
    const float* __restrict__ partial,
    int* __restrict__ idx, float* __restrict__ gate, float* __restrict__ bstats)
{
  __shared__ float xls[4][KS * Ee];
  __shared__ float sacc[49];
  const int tid = threadIdx.x;
  const int w = tid >> 6, lane = tid & 63;
  const int t = blockIdx.x * 4 + w;

  if (tid < 49) sacc[tid] = 0.f;

  const float* p = partial + (size_t)t * (KS * Ee);
  #pragma unroll
  for (int i = 0; i < 6; ++i) xls[w][lane + i * 64] = p[lane + i * 64];

  float logit = -1e30f;
  if (lane < Ee) {
    float acc = 0.f;
    #pragma unroll
    for (int s = 0; s < KS; ++s) acc += xls[w][s * Ee + lane];
    logit = acc;
  }
  float m = logit;
  for (int o = 32; o; o >>= 1) m = fmaxf(m, __shfl_xor(m, o));
  float pr = (lane < Ee) ? expf(logit - m) : 0.f;
  float s = pr;
  for (int o = 32; o; o >>= 1) s += __shfl_xor(s, o);
  float prob = pr / s;
  float lse = m + logf(s);

  bool sel = false;
  float my_p = 0.f; int my_e = -1;
  for (int h = 0; h < Hh; ++h) {
    float v = (lane < Ee && !sel) ? prob : -1.f;
    int ix = lane;
    for (int o = 32; o; o >>= 1) {
      float ov = __shfl_xor(v, o); int oi = __shfl_xor(ix, o);
      if (ov > v || (ov == v && oi < ix)) { v = ov; ix = oi; }
    }
    if (lane == ix) sel = true;
    if (lane == h) { my_p = v; my_e = ix; }
  }
  float gsum = (lane < Hh) ? my_p : 0.f;
  for (int o = 32; o; o >>= 1) gsum += __shfl_xor(gsum, o);
  if (lane < Hh) {
    idx[t * Hh + lane] = my_e;
    gate[t * Hh + lane] = my_p / (gsum + 1e-6f);
  }

  __syncthreads();
  if (lane < Ee) atomicAdd(&sacc[lane], prob);
  if (lane < Hh) atomicAdd(&sacc[24 + my_e], 1.0f);
  if (lane == 0) atomicAdd(&sacc[48], lse * lse);
  __syncthreads();
  if (tid < 49) bstats[(size_t)tid * NB2 + blockIdx.x] = sacc[tid];
}

// ---------------------------------------------------------------------------
// Flash attention, transposed, 32 q/wave (two 16-q groups share every K/V
// fragment read), in-register P via 16x16x16 MFMA, key-permuted V^T so V
// fragments are contiguous ds_read_b128 (2-way conflict-free).
// Key-split over blockIdx.z (additive no-rescale partials).
// Block = 4 waves x 32 q = 128 q.  Grid (N/128, B*H, 2) = 768 blocks.
// LDS = 16 KB.  Writes f32 partial O and l.
// ---------------------------------------------------------------------------
__global__ __launch_bounds__(256) void attn_kernel(
    const unsigned short* __restrict__ qallb, const int* __restrict__ idx,
    const unsigned short* __restrict__ kbuf, const unsigned short* __restrict__ vtbuf,
    float* __restrict__ opart, float* __restrict__ lpart)
{
  __shared__ __align__(16) unsigned short ksl[64 * 64];   // K tile  [key][d], swizzled
  __shared__ __align__(16) unsigned short vtl[64 * 64];   // V^T tile [d][key-perm], swizzled

  const int tid = threadIdx.x;
  const int w = tid >> 6, lane = tid & 63;
  const int quad = lane >> 4, nl = lane & 15;
  const int bh = blockIdx.y;
  const int b = bh / Hh, h = bh - b * Hh;
  const int qw = blockIdx.x * 128 + w * 32;     // wave's 32 queries
  const int sp = blockIdx.z;
  const int jbeg = sp * (Nn / 2);

  // Q B-frags for the two 16-q groups (gathered via expert idx; pre-scaled)
  bf16x8 qB0[2], qB1[2];
  #pragma unroll
  for (int g = 0; g < 2; ++g) {
    const int tq = b * Nn + qw + g * 16 + nl;
    const int eq = idx[tq * Hh + h];
    const unsigned short* qrow = qallb + (size_t)tq * (Ee * Dd) + eq * Dd + quad * 8;
    qB0[g] = *(const bf16x8*)(qrow);
    qB1[g] = *(const bf16x8*)(qrow + 32);
  }

  f32x4 acc[2][4];
  #pragma unroll
  for (int g = 0; g < 2; ++g)
    #pragma unroll
    for (int dg = 0; dg < 4; ++dg) acc[g][dg] = (f32x4){0.f, 0.f, 0.f, 0.f};
  float l[2] = {0.f, 0.f};

  const int sr  = lane >> 3;
  const int cbd = (lane & 7) ^ sr;              // XOR-swizzled source chunk
  const int xl  = nl & 7;
  const int ca0 = (quad ^ xl) * 8;              // K b128 chunk offsets
  const int ca1 = ((quad + 4) ^ xl) * 8;
  const int va0 = ((quad * 2) ^ xl) * 8;        // V b128 chunk offsets (kg 0,1)
  const int va1 = ((quad * 2 + 1) ^ xl) * 8;    // (kg 2,3)

  for (int j0 = jbeg; j0 < jbeg + Nn / 2; j0 += 64) {
    #pragma unroll
    for (int i = 0; i < 2; ++i) {
      int r = w * 16 + i * 8;
      gload16(kbuf + ((size_t)b * Nn + j0 + r + sr) * Dd + cbd * 8, ksl + r * 64);
      gload16(vtbuf + ((size_t)b * Dd + r + sr) * Nn + j0 + cbd * 8, vtl + r * 64);
    }
    __syncthreads();

    // --- S^T = K·Q^T; K frag loaded once, used by both q groups ---
    bf16x4 pf[2][4];
    #pragma unroll
    for (int kg = 0; kg < 4; ++kg) {
      const unsigned short* kr = ksl + (kg * 16 + nl) * 64;
      bf16x8 a0 = *(const bf16x8*)(kr + ca0);
      bf16x8 a1 = *(const bf16x8*)(kr + ca1);
      #pragma unroll
      for (int g = 0; g < 2; ++g) {
        f32x4 c = {0.f, 0.f, 0.f, 0.f};
        c = __builtin_amdgcn_mfma_f32_16x16x32_bf16(a0, qB0[g], c, 0, 0, 0);
        c = __builtin_amdgcn_mfma_f32_16x16x32_bf16(a1, qB1[g], c, 0, 0, 0);
        float p0 = __builtin_amdgcn_exp2f(c[0]);
        float p1 = __builtin_amdgcn_exp2f(c[1]);
        float p2 = __builtin_amdgcn_exp2f(c[2]);
        float p3 = __builtin_amdgcn_exp2f(c[3]);
        l[g] += (p0 + p1) + (p2 + p3);
        union { __hip_bfloat162 h2[2]; bf16x4 v; } pk;
        pk.h2[0] = __float22bfloat162_rn(float2{p0, p1});
        pk.h2[1] = __float22bfloat162_rn(float2{p2, p3});
        pf[g][kg] = pk.v;
      }
    }
    // --- O^T += V^T·P^T via 16x16x16 MFMA; V frag shared across groups ---
    #pragma unroll
    for (int dg = 0; dg < 4; ++dg) {
      const unsigned short* vrow = vtl + (dg * 16 + nl) * 64;
      bf16x8 v01 = *(const bf16x8*)(vrow + va0);   // keys kg=0 | kg=1 (permuted)
      bf16x8 v23 = *(const bf16x8*)(vrow + va1);   // keys kg=2 | kg=3
      bf16x4 av0 = __builtin_shufflevector(v01, v01, 0, 1, 2, 3);
      bf16x4 av1 = __builtin_shufflevector(v01, v01, 4, 5, 6, 7);
      bf16x4 av2 = __builtin_shufflevector(v23, v23, 0, 1, 2, 3);
      bf16x4 av3 = __builtin_shufflevector(v23, v23, 4, 5, 6, 7);
      #pragma unroll
      for (int g = 0; g < 2; ++g) {
        acc[g][dg] = __builtin_amdgcn_mfma_f32_16x16x16bf16_1k(av0, pf[g][0], acc[g][dg], 0, 0, 0);
        acc[g][dg] = __builtin_amdgcn_mfma_f32_16x16x16bf16_1k(av1, pf[g][1], acc[g][dg], 0, 0, 0);
        acc[g][dg] = __builtin_amdgcn_mfma_f32_16x16x16bf16_1k(av2, pf[g][2], acc[g][dg], 0, 0, 0);
        acc[g][dg] = __builtin_amdgcn_mfma_f32_16x16x16bf16_1k(av3, pf[g][3], acc[g][dg], 0, 0, 0);
      }
    }
    __syncthreads();
  }

  #pragma unroll
  for (int g = 0; g < 2; ++g) {
    float lg = l[g];
    lg += __shfl_xor(lg, 16);
    lg += __shfl_xor(lg, 32);
    if (lane < 16)
      lpart[(size_t)sp * (Bb * Hh * Nn) + (size_t)bh * Nn + qw + g * 16 + nl] = lg;
    float* orow = opart + (size_t)sp * ((size_t)Bb * Hh * Nn * Dd)
                + ((size_t)bh * Nn + qw + g * 16 + nl) * Dd + quad * 4;
    #pragma unroll
    for (int dg = 0; dg < 4; ++dg) {
      float4 o;
      o.x = acc[g][dg][0]; o.y = acc[g][dg][1];
      o.z = acc[g][dg][2]; o.w = acc[g][dg][3];
      *(float4*)(orow + dg * 16) = o;
    }
  }
}

// ---------------------------------------------------------------------------
// Combine: obuf[i] = (opart0[i]+opart1[i]) / (l0[row]+l1[row]), bf16 out.
// ---------------------------------------------------------------------------
__global__ __launch_bounds__(256) void combine_kernel(
    const float* __restrict__ opart, const float* __restrict__ lpart,
    unsigned short* __restrict__ obuf)
{
  const size_t gid = (size_t)blockIdx.x * 256 + threadIdx.x;
  const size_t row = gid >> 4;
  const size_t NTOT = (size_t)Bb * Hh * Nn * Dd;
  float4 o0 = ((const float4*)opart)[gid];
  float4 o1 = ((const float4*)(opart + NTOT))[gid];
  float rinv = 1.0f / (lpart[row] + lpart[(size_t)Bb * Hh * Nn + row]);
  ushort4 o;
  o.x = f2bf((o0.x + o1.x) * rinv);
  o.y = f2bf((o0.y + o1.y) * rinv);
  o.z = f2bf((o0.z + o1.z) * rinv);
  o.w = f2bf((o0.w + o1.w) * rinv);
  ((ushort4*)obuf)[gid] = o;
}

// ---------------------------------------------------------------------------
// Scatter: write the FULL dense bf16 xeg[T][KR] row
// ---------------------------------------------------------------------------
__global__ __launch_bounds__(256) void scatter_kernel(
    const unsigned short* __restrict__ obuf, const int* __restrict__ idx,
    const float* __restrict__ gate, unsigned short* __restrict__ xeg)
{
  __shared__ int   sel[Ee];
  __shared__ float gg[Hh];
  const int t = blockIdx.x, b = t >> 11, nn = t & (Nn - 1);
  const int tid = threadIdx.x;
  if (tid < Ee) sel[tid] = -1;
  __syncthreads();
  if (tid < Hh) {
    int e = idx[t * Hh + tid];
    sel[e] = tid;
    gg[tid] = gate[t * Hh + tid];
  }
  __syncthreads();
  for (int c = tid; c < KR; c += 256) {
    float v = 0.f;
    if (c < 1536) {
      int e = c >> 6, h = sel[e];
      if (h >= 0)
        v = gg[h] * bf2f(obuf[((size_t)(b * Hh + h) * Nn + nn) * Dd + (c & 63)]);
    } else if (c < 1560) {
      int h = sel[c - 1536];
      if (h >= 0) v = gg[h];
    }
    xeg[(size_t)t * KR + c] = f2bf(v);
  }
}

// ---------------------------------------------------------------------------
// aux1: parallel bstats row-sum -> stats2[49];  aux2: finalize
// ---------------------------------------------------------------------------
__global__ __launch_bounds__(256) void aux1_kernel(
    const float* __restrict__ bstats, float* __restrict__ stats2)
{
  __shared__ float r[4];
  const int j = blockIdx.x, tid = threadIdx.x;
  float4 v = *(const float4*)&bstats[(size_t)j * NB2 + tid * 4];
  float s = (v.x + v.y) + (v.z + v.w);
  for (int o = 32; o; o >>= 1) s += __shfl_xor(s, o);
  if ((tid & 63) == 0) r[tid >> 6] = s;
  __syncthreads();
  if (tid == 0) stats2[j] = (r[0] + r[1]) + (r[2] + r[3]);
}

__global__ void aux2_kernel(const float* __restrict__ stats2,
                            float* __restrict__ out, int out_size)
{
  const int lane = threadIdx.x;
  float a = (lane < Ee) ? stats2[lane] : 0.f;
  float b = (lane < Ee) ? stats2[24 + lane] : 0.f;
  float pt = a, ft = b, sw = a * b;
  for (int o = 32; o; o >>= 1) {
    pt += __shfl_xor(pt, o); ft += __shfl_xor(ft, o); sw += __shfl_xor(sw, o);
  }
  if (lane == 0) {
    float sswitch = (float)Ee * sw / (pt * ft);
    float z = stats2[48] * (1.0f / (float)T_);
    out[out_size - 1] = 0.1f * sswitch + 0.001f * z;
  }
}

// ---------------------------------------------------------------------------
extern "C" void kernel_launch(void* const* d_in, const int* in_sizes, int n_in,
                              void* d_out, int out_size, void* d_ws, size_t ws_size,
                              hipStream_t stream)
{
  const float* x     = (const float*)d_in[0];
  const float* wg    = (const float*)d_in[1];
  const float* W_in  = (const float*)d_in[2];
  const float* b_in  = (const float*)d_in[3];
  const float* W_out = (const float*)d_in[4];
  const float* b_out = (const float*)d_in[5];
  const float* W_kv  = (const float*)d_in[6];
  const float* b_kv  = (const float*)d_in[7];
  float* out = (float*)d_out;

  char* ws = (char*)d_ws;
  size_t off = 0;
  auto carve = [&](size_t bytes) -> void* {
    void* p = ws + off;
    off = (off + bytes + 255) & ~(size_t)255;
    return p;
  };
  int*            idx    = (int*)           carve((size_t)T_ * Hh * 4);
  float*          gate   = (float*)         carve((size_t)T_ * Hh * 4);
  float*          bstats = (float*)         carve((size_t)49 * NB2 * 4);
  float*          stats2 = (float*)         carve(256);
  float*          lpart  = (float*)         carve((size_t)2 * Bb * Hh * Nn * 4);
  float*          lgate  = (float*)         carve((size_t)T_ * KS * Ee * 4);
  unsigned short* xb     = (unsigned short*)carve((size_t)T_ * Cc * 2);
  unsigned short* BqkvT  = (unsigned short*)carve((size_t)(Ee * Dd + 128) * Cc * 2);
  unsigned short* BkvT   = BqkvT + (size_t)Ee * Dd * Cc;
  unsigned short* BrT    = (unsigned short*)carve((size_t)Cc * KR * 2);
  unsigned short* kbuf   = (unsigned short*)carve((size_t)T_ * Dd * 2);
  unsigned short* vtbuf  = (unsigned short*)carve((size_t)T_ * Dd * 2);
  unsigned short* qallb  = (unsigned short*)carve((size_t)T_ * Ee * Dd * 2);
  float*          opart  = (float*)         carve((size_t)2 * Bb * Hh * Nn * Dd * 4);
  unsigned short* obuf   = (unsigned short*)carve((size_t)T_ * Hh * Dd * 2);
  unsigned short* xeg    = (unsigned short*)carve((size_t)T_ * KR * 2);

  // weight conversions
  convert_win_kernel<<<dim3(Ee, Cc / 64), 256, 0, stream>>>(W_in, BqkvT);
  convert_wout_kernel<<<dim3(KR / 32, Cc / 64), 256, 0, stream>>>(W_out, b_out, BrT);
  convert_wkv_kernel<<<Cc / 64, 256, 0, stream>>>(W_kv, BkvT);

  // gating (+ fused x -> bf16)
  gate1_kernel<<<dim3(T_ / 256, KS), 256, 0, stream>>>(x, wg, lgate, xb);
  gate2_kernel<<<NB2, 256, 0, stream>>>(lgate, idx, gate, bstats);

  // fused qall + kv GEMM: 64-row tiles, grid (64, 13)
  gemm_bt_kernel<1, 64><<<dim3(T_ / 64, 13), 256, 0, stream>>>(
      xb, BqkvT, b_in, b_kv, qallb, kbuf, vtbuf, Cc, 1536);

  // attention: grid (16, 24, 2), 32 q/wave + key split
  attn_kernel<<<dim3(Nn / 128, Bb * Hh, 2), 256, 0, stream>>>(
      qallb, idx, kbuf, vtbuf, opart, lpart);
  combine_kernel<<<(Bb * Hh * Nn * Dd / 4) / 256, 256, 0, stream>>>(
      opart, lpart, obuf);

  scatter_kernel<<<T_, 256, 0, stream>>>(obuf, idx, gate, xeg);

  // out = xeg @ BrT^T -> f32: 64-row tiles, grid (64, 6)
  gemm_bt_kernel<0, 64><<<dim3(T_ / 64, Cc / 128), 256, 0, stream>>>(
      xeg, BrT, nullptr, nullptr, out, nullptr, nullptr, KR, Cc);

  // aux loss
  aux1_kernel<<<49, 256, 0, stream>>>(bstats, stats2);
  aux2_kernel<<<1, 64, 0, stream>>>(stats2, out, out_size);
}

// Round 12
// 215.617 us; speedup vs baseline: 1.0550x; 1.0550x over previous
//
#include <hip/hip_runtime.h>
#include <hip/hip_bf16.h>

// Problem constants
#define T_  4096
#define Bb  2
#define Nn  2048
#define Cc  768
#define Ee  24
#define Dd  64
#define Hh  12
#define KR  1568   // reduce GEMM K: 1536 (W_out) + 24 (b_out via dense gates) + 8 pad
#define KS  16     // gate k-split
#define KC  48     // 768 / KS
#define NB2 1024   // gate2 block count (T_/4)
#define SCL 0.18033688f   // 0.125 * log2(e) — folded into q at GEMM epilogue

typedef __attribute__((ext_vector_type(8))) short bf16x8;
typedef __attribute__((ext_vector_type(4))) short bf16x4;
typedef __attribute__((ext_vector_type(4))) float f32x4;

__device__ __forceinline__ unsigned short f2bf(float f) {
  union { float f; unsigned int i; } u; u.f = f;
  unsigned int r = u.i + 0x7FFFu + ((u.i >> 16) & 1u);
  return (unsigned short)(r >> 16);
}
__device__ __forceinline__ float bf2f(unsigned short s) {
  union { unsigned int i; float f; } u; u.i = ((unsigned int)s) << 16; return u.f;
}

__device__ __forceinline__ void gload16(const void* g, void* l) {
  __builtin_amdgcn_global_load_lds(
      (const __attribute__((address_space(1))) void*)g,
      (__attribute__((address_space(3))) void*)l, 16, 0, 0);
}

// ---------------------------------------------------------------------------
// Merged weight conversion (one dispatch): flat grid
//   blocks [0,288)          : W_in -> BqT   (e = i/12, c0 = (i%12)*64)
//   blocks [288, 288+588)   : [W_out;b_out] -> BrT (k0,n0)
//   blocks [876, 888)       : W_kv -> BkvT
// ---------------------------------------------------------------------------
__global__ __launch_bounds__(256) void convert_all_kernel(
    const float* __restrict__ W_in, const float* __restrict__ W_out,
    const float* __restrict__ b_out, const float* __restrict__ W_kv,
    unsigned short* __restrict__ BqT, unsigned short* __restrict__ BrT,
    unsigned short* __restrict__ BkvT)
{
  __shared__ float ls[64 * 129];
  const int bid = blockIdx.x, tid = threadIdx.x;
  if (bid < 288) {
    const int e = bid / 12, c0 = (bid % 12) * 64;
    #pragma unroll
    for (int i = 0; i < 16; ++i) {
      int L = tid + i * 256, c = L >> 6, d = L & 63;
      ls[c * 65 + d] = W_in[(size_t)e * Cc * Dd + (size_t)(c0 + c) * Dd + d];
    }
    __syncthreads();
    #pragma unroll
    for (int i = 0; i < 16; ++i) {
      int L = tid + i * 256, d = L >> 6, c = L & 63;
      BqT[(size_t)(e * Dd + d) * Cc + c0 + c] = f2bf(ls[c * 65 + d]);
    }
  } else if (bid < 876) {
    const int i2 = bid - 288;
    const int k0 = (i2 / 12) * 32, n0 = (i2 % 12) * 64;
    #pragma unroll
    for (int i = 0; i < 8; ++i) {
      int L = tid + i * 256, k = L >> 6, n = L & 63;
      int kk = k0 + k;
      float v = (kk < 1536) ? W_out[(size_t)kk * Cc + n0 + n]
              : (kk < 1560) ? b_out[(size_t)(kk - 1536) * Cc + n0 + n] : 0.f;
      ls[k * 65 + n] = v;
    }
    __syncthreads();
    #pragma unroll
    for (int i = 0; i < 8; ++i) {
      int L = tid + i * 256, n = L >> 5, k = L & 31;
      BrT[(size_t)(n0 + n) * KR + k0 + k] = f2bf(ls[k * 65 + n]);
    }
  } else {
    const int c0 = (bid - 876) * 64;
    #pragma unroll
    for (int i = 0; i < 32; ++i) {
      int L = tid + i * 256, c = L >> 7, j = L & 127;
      ls[c * 129 + j] = W_kv[(size_t)(c0 + c) * 128 + j];
    }
    __syncthreads();
    #pragma unroll
    for (int i = 0; i < 32; ++i) {
      int L = tid + i * 256, j = L >> 6, c = L & 63;
      BkvT[(size_t)j * Cc + c0 + c] = f2bf(ls[c * 129 + j]);
    }
  }
}

// ---------------------------------------------------------------------------
// bf16 MFMA GEMM: C = A[M][K] @ BT[N][K]^T (+bias).  Tile BM x 128, BK=32.
// MODE 0: f32 out (reduce GEMM).
// MODE 1: fused qall+kv.  BT = [BqT(1536) ; BkvT(128)] contiguous.
//   col < 1536 -> qallb (+b_in), PRE-SCALED by SCL
//   1536..1599 -> kbuf [B][N][D] (+b_kv lo)
//   1600..1663 -> vtbuf [B][D][N] (+b_kv hi), KEY-PERMUTED within each
//     64-key block: store position np for physical key p=nn&63 with
//     np = (p & 0x23) | (((p>>4)&1)<<2) | (((p>>2)&3)<<3)
//     -> a lane's S^T granules concatenate into valid K=32 PV B-frags.
// ---------------------------------------------------------------------------
template<int MODE, int BM>
__global__ __launch_bounds__(256) void gemm_bt_kernel(
    const unsigned short* __restrict__ A, const unsigned short* __restrict__ BT,
    const float* __restrict__ bias, const float* __restrict__ bias2,
    void* __restrict__ Cout, void* __restrict__ Cout2, void* __restrict__ Cout3,
    int K, int ldc)
{
  constexpr int MI = BM / 32;
  __shared__ __align__(16) unsigned short As[BM * 32];
  __shared__ __align__(16) unsigned short Bs[128 * 32];
  const int tid = threadIdx.x, w = tid >> 6, lane = tid & 63;
  const int quad = lane >> 4, nl = lane & 15;
  const int m0 = blockIdx.x * BM, n0 = blockIdx.y * 128;
  const int mw = (w & 1) * (BM / 2), nw = (w >> 1) * 64;

  f32x4 acc[MI][4];
  #pragma unroll
  for (int i = 0; i < MI; ++i)
    #pragma unroll
    for (int j = 0; j < 4; ++j) acc[i][j] = (f32x4){0.f, 0.f, 0.f, 0.f};

  const int rlane = lane >> 2, col8 = (lane & 3) * 8;
  const int row0a = w * (BM / 4) + rlane;
  const int row0b = w * 32 + rlane;
  const unsigned short* a0 = A + (size_t)(m0 + row0a) * K + col8;
  const unsigned short* a1 = a0 + (size_t)16 * K;
  const unsigned short* b0 = BT + (size_t)(n0 + row0b) * K + col8;
  const unsigned short* b1 = b0 + (size_t)16 * K;
  unsigned short* lA0 = As + (w * (BM / 4)) * 32;
  unsigned short* lA1 = As + (w * (BM / 4) + 16) * 32;
  unsigned short* lB0 = Bs + (w * 32) * 32;
  unsigned short* lB1 = Bs + (w * 32 + 16) * 32;

  for (int k0 = 0; k0 < K; k0 += 32) {
    gload16(a0 + k0, lA0);
    if (BM == 128) gload16(a1 + k0, lA1);
    gload16(b0 + k0, lB0);
    gload16(b1 + k0, lB1);
    __syncthreads();

    bf16x8 af[MI], bfr[4];
    #pragma unroll
    for (int mi = 0; mi < MI; ++mi)
      af[mi] = *(const bf16x8*)&As[(mw + mi * 16 + nl) * 32 + quad * 8];
    #pragma unroll
    for (int ni = 0; ni < 4; ++ni)
      bfr[ni] = *(const bf16x8*)&Bs[(nw + ni * 16 + nl) * 32 + quad * 8];
    #pragma unroll
    for (int mi = 0; mi < MI; ++mi)
      #pragma unroll
      for (int ni = 0; ni < 4; ++ni)
        acc[mi][ni] = __builtin_amdgcn_mfma_f32_16x16x32_bf16(
            af[mi], bfr[ni], acc[mi][ni], 0, 0, 0);
    __syncthreads();
  }

  #pragma unroll
  for (int mi = 0; mi < MI; ++mi) {
    int rowb = m0 + mw + mi * 16 + quad * 4;
    int bb = rowb >> 11, nn = rowb & (Nn - 1);
    #pragma unroll
    for (int ni = 0; ni < 4; ++ni) {
      int col = n0 + nw + ni * 16 + nl;
      if (MODE == 0) {
        #pragma unroll
        for (int reg = 0; reg < 4; ++reg)
          ((float*)Cout)[(size_t)(rowb + reg) * ldc + col] = acc[mi][ni][reg];
      } else {
        if (col < 1536) {
          float bv = bias[col];
          #pragma unroll
          for (int reg = 0; reg < 4; ++reg)
            ((unsigned short*)Cout)[(size_t)(rowb + reg) * 1536 + col] =
                f2bf((acc[mi][ni][reg] + bv) * SCL);
        } else {
          int c2 = col - 1536;
          float bv = bias2[c2];
          if (c2 < Dd) {
            #pragma unroll
            for (int reg = 0; reg < 4; ++reg)
              ((unsigned short*)Cout2)[((size_t)bb * Nn + nn + reg) * Dd + c2] =
                  f2bf(acc[mi][ni][reg] + bv);
          } else {
            int p6 = nn & 63;
            int np = (nn & ~63) | (p6 & 0x23)
                   | (((p6 >> 4) & 1) << 2) | (((p6 >> 2) & 3) << 3);
            ushort4 v;
            v.x = f2bf(acc[mi][ni][0] + bv);
            v.y = f2bf(acc[mi][ni][1] + bv);
            v.z = f2bf(acc[mi][ni][2] + bv);
            v.w = f2bf(acc[mi][ni][3] + bv);
            *(ushort4*)((unsigned short*)Cout3 +
                        ((size_t)bb * Dd + (c2 - Dd)) * Nn + np) = v;
          }
        }
      }
    }
  }
}

// ---------------------------------------------------------------------------
// gate1: partial logits + fused x->bf16 conversion
// ---------------------------------------------------------------------------
#define XPAD 52
__global__ __launch_bounds__(256) void gate1_kernel(
    const float* __restrict__ x, const float* __restrict__ wg,
    float* __restrict__ partial, unsigned short* __restrict__ xb)
{
  __shared__ __align__(16) float xs[256 * XPAD];
  __shared__ __align__(16) float wsT[Ee * KC];
  const int tid = threadIdx.x;
  const int t0 = blockIdx.x * 256;
  const int s = blockIdx.y, k0 = s * KC;

  #pragma unroll
  for (int i = 0; i < 12; ++i) {
    int f = tid + i * 256;
    int token = f / 12, j = f % 12;
    size_t gofs = (size_t)(t0 + token) * Cc + k0 + j * 4;
    float4 v = *(const float4*)&x[gofs];
    *(float4*)&xs[token * XPAD + j * 4] = v;
    ushort4 o;
    o.x = f2bf(v.x); o.y = f2bf(v.y); o.z = f2bf(v.z); o.w = f2bf(v.w);
    *(ushort4*)&xb[gofs] = o;
  }
  for (int i = tid; i < Ee * KC; i += 256)
    wsT[(i % Ee) * KC + i / Ee] = wg[k0 * Ee + i];
  __syncthreads();

  float xr[KC];
  #pragma unroll
  for (int kg = 0; kg < KC / 4; ++kg)
    *(float4*)&xr[kg * 4] = *(const float4*)&xs[tid * XPAD + kg * 4];

  float acc[Ee];
  #pragma unroll
  for (int e = 0; e < Ee; ++e) acc[e] = 0.f;
  #pragma unroll
  for (int e = 0; e < Ee; ++e) {
    #pragma unroll
    for (int kg = 0; kg < KC / 4; ++kg) {
      float4 wv = *(const float4*)&wsT[e * KC + kg * 4];
      acc[e] += xr[kg * 4 + 0] * wv.x + xr[kg * 4 + 1] * wv.y
              + xr[kg * 4 + 2] * wv.z + xr[kg * 4 + 3] * wv.w;
    }
  }

  float* dst = partial + ((size_t)(t0 + tid) * KS + s) * Ee;
  #pragma unroll
  for (int eg = 0; eg < Ee / 4; ++eg)
    *(float4*)&dst[eg * 4] = *(float4*)&acc[eg * 4];
}

// ---------------------------------------------------------------------------
// gate2: logits -> softmax -> top-12 -> gates; block stats -> bstats
// ---------------------------------------------------------------------------
__global__ __launch_bounds__(256) void gate2_kernel(
    const float* __restrict__ partial,
    int* __restrict__ idx, float* __restrict__ gate, float* __restrict__ bstats)
{
  __shared__ float xls[4][KS * Ee];
  __shared__ float sacc[49];
  const int tid = threadIdx.x;
  const int w = tid >> 6, lane = tid & 63;
  const int t = blockIdx.x * 4 + w;

  if (tid < 49) sacc[tid] = 0.f;

  const float* p = partial + (size_t)t * (KS * Ee);
  #pragma unroll
  for (int i = 0; i < 6; ++i) xls[w][lane + i * 64] = p[lane + i * 64];

  float logit = -1e30f;
  if (lane < Ee) {
    float acc = 0.f;
    #pragma unroll
    for (int s = 0; s < KS; ++s) acc += xls[w][s * Ee + lane];
    logit = acc;
  }
  float m = logit;
  for (int o = 32; o; o >>= 1) m = fmaxf(m, __shfl_xor(m, o));
  float pr = (lane < Ee) ? expf(logit - m) : 0.f;
  float s = pr;
  for (int o = 32; o; o >>= 1) s += __shfl_xor(s, o);
  float prob = pr / s;
  float lse = m + logf(s);

  bool sel = false;
  float my_p = 0.f; int my_e = -1;
  for (int h = 0; h < Hh; ++h) {
    float v = (lane < Ee && !sel) ? prob : -1.f;
    int ix = lane;
    for (int o = 32; o; o >>= 1) {
      float ov = __shfl_xor(v, o); int oi = __shfl_xor(ix, o);
      if (ov > v || (ov == v && oi < ix)) { v = ov; ix = oi; }
    }
    if (lane == ix) sel = true;
    if (lane == h) { my_p = v; my_e = ix; }
  }
  float gsum = (lane < Hh) ? my_p : 0.f;
  for (int o = 32; o; o >>= 1) gsum += __shfl_xor(gsum, o);
  if (lane < Hh) {
    idx[t * Hh + lane] = my_e;
    gate[t * Hh + lane] = my_p / (gsum + 1e-6f);
  }

  __syncthreads();
  if (lane < Ee) atomicAdd(&sacc[lane], prob);
  if (lane < Hh) atomicAdd(&sacc[24 + my_e], 1.0f);
  if (lane == 0) atomicAdd(&sacc[48], lse * lse);
  __syncthreads();
  if (tid < 49) bstats[(size_t)tid * NB2 + blockIdx.x] = sacc[tid];
}

// ---------------------------------------------------------------------------
// Flash attention, transposed, 32 q/wave, in-register P, and PV at K=32:
// the V^T key-permutation (GEMM epilogue) makes each lane's four 4-key S^T
// granules concatenate into two valid K=32 B-frags, so PV is 16 full-rate
// 16x16x32 MFMAs/tile (was 32 half-K).  V fragment reads use the same
// swizzled b128 offsets as K.  Key-split over blockIdx.z (additive partials).
// Grid (N/128, B*H, 2) = 768 blocks.  LDS = 16 KB.
// ---------------------------------------------------------------------------
__global__ __launch_bounds__(256) void attn_kernel(
    const unsigned short* __restrict__ qallb, const int* __restrict__ idx,
    const unsigned short* __restrict__ kbuf, const unsigned short* __restrict__ vtbuf,
    float* __restrict__ opart, float* __restrict__ lpart)
{
  __shared__ __align__(16) unsigned short ksl[64 * 64];   // K tile  [key][d], swizzled
  __shared__ __align__(16) unsigned short vtl[64 * 64];   // V^T tile [d][key-perm], swizzled

  const int tid = threadIdx.x;
  const int w = tid >> 6, lane = tid & 63;
  const int quad = lane >> 4, nl = lane & 15;
  const int bh = blockIdx.y;
  const int b = bh / Hh, h = bh - b * Hh;
  const int qw = blockIdx.x * 128 + w * 32;     // wave's 32 queries
  const int sp = blockIdx.z;
  const int jbeg = sp * (Nn / 2);

  // Q B-frags for the two 16-q groups (gathered via expert idx; pre-scaled)
  bf16x8 qB0[2], qB1[2];
  #pragma unroll
  for (int g = 0; g < 2; ++g) {
    const int tq = b * Nn + qw + g * 16 + nl;
    const int eq = idx[tq * Hh + h];
    const unsigned short* qrow = qallb + (size_t)tq * (Ee * Dd) + eq * Dd + quad * 8;
    qB0[g] = *(const bf16x8*)(qrow);
    qB1[g] = *(const bf16x8*)(qrow + 32);
  }

  f32x4 acc[2][4];
  #pragma unroll
  for (int g = 0; g < 2; ++g)
    #pragma unroll
    for (int dg = 0; dg < 4; ++dg) acc[g][dg] = (f32x4){0.f, 0.f, 0.f, 0.f};
  float l[2] = {0.f, 0.f};

  const int sr  = lane >> 3;
  const int cbd = (lane & 7) ^ sr;              // XOR-swizzled source chunk
  const int xl  = nl & 7;
  const int ca0 = (quad ^ xl) * 8;              // b128 chunk offsets (K and V)
  const int ca1 = ((quad + 4) ^ xl) * 8;

  for (int j0 = jbeg; j0 < jbeg + Nn / 2; j0 += 64) {
    #pragma unroll
    for (int i = 0; i < 2; ++i) {
      int r = w * 16 + i * 8;
      gload16(kbuf + ((size_t)b * Nn + j0 + r + sr) * Dd + cbd * 8, ksl + r * 64);
      gload16(vtbuf + ((size_t)b * Dd + r + sr) * Nn + j0 + cbd * 8, vtl + r * 64);
    }
    __syncthreads();

    // --- S^T = K·Q^T; K frag loaded once, used by both q groups ---
    bf16x4 pf[2][4];
    #pragma unroll
    for (int kg = 0; kg < 4; ++kg) {
      const unsigned short* kr = ksl + (kg * 16 + nl) * 64;
      bf16x8 a0 = *(const bf16x8*)(kr + ca0);
      bf16x8 a1 = *(const bf16x8*)(kr + ca1);
      #pragma unroll
      for (int g = 0; g < 2; ++g) {
        f32x4 c = {0.f, 0.f, 0.f, 0.f};
        c = __builtin_amdgcn_mfma_f32_16x16x32_bf16(a0, qB0[g], c, 0, 0, 0);
        c = __builtin_amdgcn_mfma_f32_16x16x32_bf16(a1, qB1[g], c, 0, 0, 0);
        float p0 = __builtin_amdgcn_exp2f(c[0]);
        float p1 = __builtin_amdgcn_exp2f(c[1]);
        float p2 = __builtin_amdgcn_exp2f(c[2]);
        float p3 = __builtin_amdgcn_exp2f(c[3]);
        l[g] += (p0 + p1) + (p2 + p3);
        union { __hip_bfloat162 h2[2]; bf16x4 v; } pk;
        pk.h2[0] = __float22bfloat162_rn(float2{p0, p1});
        pk.h2[1] = __float22bfloat162_rn(float2{p2, p3});
        pf[g][kg] = pk.v;
      }
    }
    // concat granules into K=32 B-frags (register-level)
    bf16x8 pb[2][2];
    #pragma unroll
    for (int g = 0; g < 2; ++g) {
      pb[g][0] = __builtin_shufflevector(pf[g][0], pf[g][1], 0, 1, 2, 3, 4, 5, 6, 7);
      pb[g][1] = __builtin_shufflevector(pf[g][2], pf[g][3], 0, 1, 2, 3, 4, 5, 6, 7);
    }
    // --- O^T += V^T·P^T at K=32; V frag shared across groups ---
    #pragma unroll
    for (int dg = 0; dg < 4; ++dg) {
      const unsigned short* vrow = vtl + (dg * 16 + nl) * 64;
      bf16x8 v0 = *(const bf16x8*)(vrow + ca0);   // permuted keys, half 0
      bf16x8 v1 = *(const bf16x8*)(vrow + ca1);   // half 1
      #pragma unroll
      for (int g = 0; g < 2; ++g) {
        acc[g][dg] = __builtin_amdgcn_mfma_f32_16x16x32_bf16(v0, pb[g][0], acc[g][dg], 0, 0, 0);
        acc[g][dg] = __builtin_amdgcn_mfma_f32_16x16x32_bf16(v1, pb[g][1], acc[g][dg], 0, 0, 0);
      }
    }
    __syncthreads();
  }

  #pragma unroll
  for (int g = 0; g < 2; ++g) {
    float lg = l[g];
    lg += __shfl_xor(lg, 16);
    lg += __shfl_xor(lg, 32);
    if (lane < 16)
      lpart[(size_t)sp * (Bb * Hh * Nn) + (size_t)bh * Nn + qw + g * 16 + nl] = lg;
    float* orow = opart + (size_t)sp * ((size_t)Bb * Hh * Nn * Dd)
                + ((size_t)bh * Nn + qw + g * 16 + nl) * Dd + quad * 4;
    #pragma unroll
    for (int dg = 0; dg < 4; ++dg) {
      float4 o;
      o.x = acc[g][dg][0]; o.y = acc[g][dg][1];
      o.z = acc[g][dg][2]; o.w = acc[g][dg][3];
      *(float4*)(orow + dg * 16) = o;
    }
  }
}

// ---------------------------------------------------------------------------
// Scatter + combine: xeg row from (opart0+opart1)/(l0+l1) with gate folded in.
// ---------------------------------------------------------------------------
__global__ __launch_bounds__(256) void scatter_kernel(
    const float* __restrict__ opart, const float* __restrict__ lpart,
    const int* __restrict__ idx, const float* __restrict__ gate,
    unsigned short* __restrict__ xeg)
{
  __shared__ int   sel[Ee];
  __shared__ float glh[Hh];   // gate / l
  __shared__ float gg[Hh];    // raw gate (for the dense-gate K-rows)
  const int t = blockIdx.x, b = t >> 11, nn = t & (Nn - 1);
  const int tid = threadIdx.x;
  const size_t HN = (size_t)Bb * Hh * Nn;
  if (tid < Ee) sel[tid] = -1;
  __syncthreads();
  if (tid < Hh) {
    int e = idx[t * Hh + tid];
    sel[e] = tid;
    float g = gate[t * Hh + tid];
    gg[tid] = g;
    size_t row = (size_t)(b * Hh + tid) * Nn + nn;
    glh[tid] = g / (lpart[row] + lpart[HN + row]);
  }
  __syncthreads();
  for (int c = tid; c < KR; c += 256) {
    float v = 0.f;
    if (c < 1536) {
      int e = c >> 6, h = sel[e];
      if (h >= 0) {
        size_t oofs = ((size_t)(b * Hh + h) * Nn + nn) * Dd + (c & 63);
        v = glh[h] * (opart[oofs] + opart[HN * Dd + oofs]);
      }
    } else if (c < 1560) {
      int h = sel[c - 1536];
      if (h >= 0) v = gg[h];
    }
    xeg[(size_t)t * KR + c] = f2bf(v);
  }
}

// ---------------------------------------------------------------------------
// aux1: parallel bstats row-sum -> stats2[49];  aux2: finalize
// ---------------------------------------------------------------------------
__global__ __launch_bounds__(256) void aux1_kernel(
    const float* __restrict__ bstats, float* __restrict__ stats2)
{
  __shared__ float r[4];
  const int j = blockIdx.x, tid = threadIdx.x;
  float4 v = *(const float4*)&bstats[(size_t)j * NB2 + tid * 4];
  float s = (v.x + v.y) + (v.z + v.w);
  for (int o = 32; o; o >>= 1) s += __shfl_xor(s, o);
  if ((tid & 63) == 0) r[tid >> 6] = s;
  __syncthreads();
  if (tid == 0) stats2[j] = (r[0] + r[1]) + (r[2] + r[3]);
}

__global__ void aux2_kernel(const float* __restrict__ stats2,
                            float* __restrict__ out, int out_size)
{
  const int lane = threadIdx.x;
  float a = (lane < Ee) ? stats2[lane] : 0.f;
  float b = (lane < Ee) ? stats2[24 + lane] : 0.f;
  float pt = a, ft = b, sw = a * b;
  for (int o = 32; o; o >>= 1) {
    pt += __shfl_xor(pt, o); ft += __shfl_xor(ft, o); sw += __shfl_xor(sw, o);
  }
  if (lane == 0) {
    float sswitch = (float)Ee * sw / (pt * ft);
    float z = stats2[48] * (1.0f / (float)T_);
    out[out_size - 1] = 0.1f * sswitch + 0.001f * z;
  }
}

// ---------------------------------------------------------------------------
extern "C" void kernel_launch(void* const* d_in, const int* in_sizes, int n_in,
                              void* d_out, int out_size, void* d_ws, size_t ws_size,
                              hipStream_t stream)
{
  const float* x     = (const float*)d_in[0];
  const float* wg    = (const float*)d_in[1];
  const float* W_in  = (const float*)d_in[2];
  const float* b_in  = (const float*)d_in[3];
  const float* W_out = (const float*)d_in[4];
  const float* b_out = (const float*)d_in[5];
  const float* W_kv  = (const float*)d_in[6];
  const float* b_kv  = (const float*)d_in[7];
  float* out = (float*)d_out;

  char* ws = (char*)d_ws;
  size_t off = 0;
  auto carve = [&](size_t bytes) -> void* {
    void* p = ws + off;
    off = (off + bytes + 255) & ~(size_t)255;
    return p;
  };
  int*            idx    = (int*)           carve((size_t)T_ * Hh * 4);
  float*          gate   = (float*)         carve((size_t)T_ * Hh * 4);
  float*          bstats = (float*)         carve((size_t)49 * NB2 * 4);
  float*          stats2 = (float*)         carve(256);
  float*          lpart  = (float*)         carve((size_t)2 * Bb * Hh * Nn * 4);
  float*          lgate  = (float*)         carve((size_t)T_ * KS * Ee * 4);
  unsigned short* xb     = (unsigned short*)carve((size_t)T_ * Cc * 2);
  unsigned short* BqkvT  = (unsigned short*)carve((size_t)(Ee * Dd + 128) * Cc * 2);
  unsigned short* BkvT   = BqkvT + (size_t)Ee * Dd * Cc;
  unsigned short* BrT    = (unsigned short*)carve((size_t)Cc * KR * 2);
  unsigned short* kbuf   = (unsigned short*)carve((size_t)T_ * Dd * 2);
  unsigned short* vtbuf  = (unsigned short*)carve((size_t)T_ * Dd * 2);
  unsigned short* qallb  = (unsigned short*)carve((size_t)T_ * Ee * Dd * 2);
  float*          opart  = (float*)         carve((size_t)2 * Bb * Hh * Nn * Dd * 4);
  unsigned short* xeg    = (unsigned short*)carve((size_t)T_ * KR * 2);

  // merged weight conversions (one dispatch)
  convert_all_kernel<<<888, 256, 0, stream>>>(
      W_in, W_out, b_out, W_kv, BqkvT, BrT, BkvT);

  // gating (+ fused x -> bf16)
  gate1_kernel<<<dim3(T_ / 256, KS), 256, 0, stream>>>(x, wg, lgate, xb);
  gate2_kernel<<<NB2, 256, 0, stream>>>(lgate, idx, gate, bstats);

  // fused qall + kv GEMM: 64-row tiles, grid (64, 13)
  gemm_bt_kernel<1, 64><<<dim3(T_ / 64, 13), 256, 0, stream>>>(
      xb, BqkvT, b_in, b_kv, qallb, kbuf, vtbuf, Cc, 1536);

  // attention: grid (16, 24, 2), 32 q/wave + key split, K=32 PV
  attn_kernel<<<dim3(Nn / 128, Bb * Hh, 2), 256, 0, stream>>>(
      qallb, idx, kbuf, vtbuf, opart, lpart);

  // scatter (+ fused partial-combine)
  scatter_kernel<<<T_, 256, 0, stream>>>(opart, lpart, idx, gate, xeg);

  // out = xeg @ BrT^T -> f32: 64-row tiles, grid (64, 6)
  gemm_bt_kernel<0, 64><<<dim3(T_ / 64, Cc / 128), 256, 0, stream>>>(
      xeg, BrT, nullptr, nullptr, out, nullptr, nullptr, KR, Cc);

  // aux loss
  aux1_kernel<<<49, 256, 0, stream>>>(bstats, stats2);
  aux2_kernel<<<1, 64, 0, stream>>>(stats2, out, out_size);
}